// Round 13
// baseline (147.273 us; speedup 1.0000x reference)
//
#include <hip/hip_runtime.h>
#include <math.h>

#define LMAX  32768
#define WWIN  1024
#define KFIR  128
#define TO    512                // outputs per block (all 4 waves share them)
#define SEGX  640                // staged samples per pair: t in [base-127, base+513)
#define CPAD  656                // padded shift-copy length (halves); 1312 B (16B mult)
#define NMAX  1024               // max notes

typedef _Float16 v8h __attribute__((ext_vector_type(8)));
typedef _Float16 v4h __attribute__((ext_vector_type(4)));
typedef float    v4f __attribute__((ext_vector_type(4)));

// ---------------- per-note parameter kernel ----------------
// amps pre-multiplied by normalized velocity (exact fold).
__global__ __launch_bounds__(256) void params_k(
    const float* __restrict__ freq, const float* __restrict__ velo,
    const float* __restrict__ w1,  const float* __restrict__ b1,
    const float* __restrict__ w2,  const float* __restrict__ b2,
    const float* __restrict__ ws1, const float* __restrict__ bs1,
    const float* __restrict__ ws2, const float* __restrict__ bs2,
    const int* __restrict__ starts, const int* __restrict__ lengths,
    int Dn, int N,
    float* __restrict__ amps_out, int* __restrict__ outlen_out)
{
    __shared__ float s_w1[32], s_b1[32], s_w2[64], s_b2[2];
    __shared__ float s_ws1[256], s_bs1[64], s_ws2[512], s_bs2[8];

    const int tid = threadIdx.x;
    if (tid < 32)  { s_w1[tid] = w1[tid]; s_b1[tid] = b1[tid]; }
    if (tid < 64)  { s_w2[tid] = w2[tid]; s_bs1[tid] = bs1[tid]; }
    if (tid < 2)   s_b2[tid] = b2[tid];
    if (tid < 8)   s_bs2[tid] = bs2[tid];
    s_ws1[tid] = ws1[tid];
    s_ws2[tid] = ws2[tid];
    s_ws2[tid + 256] = ws2[tid + 256];
    __syncthreads();

    const int n = blockIdx.x * blockDim.x + tid;
    if (n >= N) return;

    int st  = starts[n];
    int len = lengths[n];
    int ol  = min(st + len, Dn) - st;
    ol = max(0, min(ol, LMAX));
    outlen_out[n] = ol;

    float v = velo[n] * (1.0f / 127.0f);
    float nt = (float)st / (float)Dn;

    float lat0 = s_b2[0], lat1 = s_b2[1];
    #pragma unroll
    for (int j = 0; j < 32; ++j) {
        float h = fmaxf(fmaf(nt, s_w1[j], s_b1[j]), 0.0f);
        lat0 = fmaf(h, s_w2[j * 2 + 0], lat0);
        lat1 = fmaf(h, s_w2[j * 2 + 1], lat1);
    }

    const float f0 = freq[n], f1 = v, f2 = lat0, f3 = lat1;

    float acc[8];
    #pragma unroll
    for (int h = 0; h < 8; ++h) acc[h] = s_bs2[h];
    #pragma unroll
    for (int j = 0; j < 64; ++j) {
        float a = s_bs1[j];
        a = fmaf(f0, s_ws1[0 * 64 + j], a);
        a = fmaf(f1, s_ws1[1 * 64 + j], a);
        a = fmaf(f2, s_ws1[2 * 64 + j], a);
        a = fmaf(f3, s_ws1[3 * 64 + j], a);
        a = fmaxf(a, 0.0f);
        #pragma unroll
        for (int h = 0; h < 8; ++h)
            acc[h] = fmaf(a, s_ws2[j * 8 + h], acc[h]);
    }
    #pragma unroll
    for (int h = 0; h < 8; ++h) {
        float a = acc[h];
        float sp = fmaxf(a, 0.0f) + log1pf(expf(-fabsf(a)));
        amps_out[n * 8 + h] = sp * v;            // velocity folded in
    }
}

__device__ __forceinline__ float fast_tanh(float x) {
    float e = __builtin_amdgcn_exp2f(x * 2.8853900817779268f);  // 2*log2(e)
    return fmaf(-2.0f, __builtin_amdgcn_rcpf(e + 1.0f), 1.0f);
}

// ---------------- gather synthesis kernel (MFMA FIR, note-parallel waves) ----------------
// Block = 4 waves serving the SAME 512 outputs; wave w handles notes
// kk = w, w+4, ...  (r12 economics: 640-sample staging per pair, 4 fp16
// shift-copies, 24 MFMA dual-chunk FIR, interior fast path).  Waves never
// barrier in the pair loop; partial sums go to red[wid][512] (non-atomic),
// one barrier, 4-way sum + coalesced store.  4x the wave supply of r12 at
// identical total work -- attacks the 16%-occupancy latency wall.
__global__ __launch_bounds__(256, 4) void synth_gather_k(
    const float* __restrict__ freq_g, const int* __restrict__ starts,
    const float* __restrict__ amps_g, const int* __restrict__ outlen_g,
    const float* __restrict__ fir,
    float* __restrict__ out, int Dn, int N)
{
    __shared__ __align__(16) _Float16 segc[4][4][CPAD];   // 21 KB
    __shared__ float red[4][TO];                          // 8 KB
    __shared__ float fir_s[KFIR];
    __shared__ unsigned short note_list[NMAX];
    __shared__ int note_cnt;

    const int tid  = threadIdx.x;
    const int wid  = tid >> 6;
    const int lane = tid & 63;
    const int m    = lane & 15;
    const int quad = lane >> 4;
    const int o0   = blockIdx.x * TO;
    const int o_end = min(o0 + TO, Dn);

    if (tid < KFIR) fir_s[tid] = fir[tid];
    if (tid == 0) note_cnt = 0;
    __syncthreads();
    for (int j = tid; j < N; j += 256) {
        int st = starts[j];
        int ol = outlen_g[j];
        if (st < o_end && st + ol > o0) {
            int p = atomicAdd(&note_cnt, 1);
            note_list[p] = (unsigned short)j;
        }
    }
    __syncthreads();
    const int K = note_cnt;

    // ---- A fragments: shifted filter bank (constant for whole kernel) ----
    v8h afrag[12];
    #pragma unroll
    for (int t = 0; t < 12; ++t) {
        v8h af;
        #pragma unroll
        for (int j = 0; j < 8; ++j) {
            int idx = 32 * t + 8 * quad + j - 16 * m;
            float fv = (idx >= 0 && idx < KFIR) ? fir_s[idx] : 0.0f;
            af[j] = (_Float16)fv;
        }
        afrag[t] = af;
    }

    // ---- zero pad tails [636,656) of this wave's shift-copies ----
    for (int z = lane; z < 4 * 20; z += 64) {
        int S = z / 20, off = z % 20;
        segc[wid][S][636 + off] = (_Float16)0.0f;
    }

    // per-lane B read base: copy c = m&3, in-copy half index (m&~3)+8*quad (8B aligned)
    const _Float16* __restrict__ bbase = &segc[wid][m & 3][(m & ~3) + 8 * quad];

    float accA0 = 0.f, accA1 = 0.f, accA2 = 0.f, accA3 = 0.f;
    float accB0 = 0.f, accB1 = 0.f, accB2 = 0.f, accB3 = 0.f;

    const double inv2pi = 0.15915494309189535;
    const float4* __restrict__ amps4 = (const float4*)amps_g;

    // ---- prefetch this wave's pair 0 parameters ----
    int stN = 0, olN = 0; float fN = 0.f;
    float4 amN0 = {}, amN1 = {};
    if (wid < K) {
        const int nid = __builtin_amdgcn_readfirstlane((int)note_list[wid]);
        stN = starts[nid]; olN = outlen_g[nid];
        fN = freq_g[nid];
        amN0 = amps4[nid * 2]; amN1 = amps4[nid * 2 + 1];
    }

    for (int kk = wid; kk < K; kk += 4) {
        const int st = stN, ol = olN;
        const float f = fN;
        const float4 am0 = amN0, am1 = amN1;
        if (kk + 4 < K) {
            const int nid = __builtin_amdgcn_readfirstlane((int)note_list[kk + 4]);
            stN = starts[nid]; olN = outlen_g[nid];
            fN = freq_g[nid];
            amN0 = amps4[nid * 2]; amN1 = amps4[nid * 2 + 1];
        }

        const int base = o0 - st;             // note-local index of tile's first output
        if (base >= ol || base + TO <= 0) continue;   // wave-uniform skip

        const float A0 = am0.x, A1 = am0.y, A2 = am0.z, A3 = am0.w;
        const float A4 = am1.x, A5 = am1.y, A6 = am1.z, A7 = am1.w;
        const double fd = (double)f;

        // phase seed (f64 once per pair) + fixed-angle rotation stepping
        const int tseed = base - 127 + lane;
        double rev0 = fd * (double)tseed * inv2pi;
        float r0 = (float)(rev0 - floor(rev0));
        float s = __builtin_amdgcn_sinf(r0);
        float c = __builtin_amdgcn_cosf(r0);
        double d64 = fd * 64.0 * inv2pi;
        float r64 = (float)(d64 - floor(d64));
        const float sd = __builtin_amdgcn_sinf(r64);
        const float cd = __builtin_amdgcn_cosf(r64);
        const int wbase = ol - WWIN;

        // wave-uniform fast path: no bounds checks, no Hann window
        const bool interior = (base >= 127) && (base + 513 <= wbase);

        if (interior) {
            #pragma unroll
            for (int i = 0; i < 10; ++i) {
                float tc = c + c;
                float sA = s;
                float sum = A0 * sA;
                float sB = tc * sA;              sum = fmaf(A1, sB, sum);
                float sC = fmaf(tc, sB, -sA);    sum = fmaf(A2, sC, sum);
                float sD = fmaf(tc, sC, -sB);    sum = fmaf(A3, sD, sum);
                float sE = fmaf(tc, sD, -sC);    sum = fmaf(A4, sE, sum);
                float sF = fmaf(tc, sE, -sD);    sum = fmaf(A5, sF, sum);
                float sG = fmaf(tc, sF, -sE);    sum = fmaf(A6, sG, sum);
                float sH = fmaf(tc, sG, -sF);    sum = fmaf(A7, sH, sum);
                _Float16 h = (_Float16)sum;
                const int x = lane + 64 * i;
                if (i == 0) {
                    #pragma unroll
                    for (int S = 0; S < 4; ++S)
                        if (x >= S) segc[wid][S][x - S] = h;
                } else {
                    #pragma unroll
                    for (int S = 0; S < 4; ++S)
                        segc[wid][S][x - S] = h;
                }
                float ns = fmaf(s, cd, c * sd);
                float nc = fmaf(c, cd, -(s * sd));
                s = ns; c = nc;
            }
        } else {
            #pragma unroll
            for (int i = 0; i < 10; ++i) {
                int t = tseed + 64 * i;
                float val = 0.0f;
                if (t >= 0 && t < ol) {
                    float tc = c + c;
                    float sA = s;
                    float sum = A0 * sA;
                    float sB = tc * sA;              sum = fmaf(A1, sB, sum);
                    float sC = fmaf(tc, sB, -sA);    sum = fmaf(A2, sC, sum);
                    float sD = fmaf(tc, sC, -sB);    sum = fmaf(A3, sD, sum);
                    float sE = fmaf(tc, sD, -sC);    sum = fmaf(A4, sE, sum);
                    float sF = fmaf(tc, sE, -sD);    sum = fmaf(A5, sF, sum);
                    float sG = fmaf(tc, sF, -sE);    sum = fmaf(A6, sG, sum);
                    float sH = fmaf(tc, sG, -sF);    sum = fmaf(A7, sH, sum);
                    int wpos = t - wbase;
                    float factor = 1.0f;
                    if (wpos >= 0)
                        factor = 0.5f - 0.5f * __builtin_amdgcn_cosf((float)wpos * (1.0f / WWIN));
                    val = sum * factor;
                }
                _Float16 h = (_Float16)val;
                const int x = lane + 64 * i;
                if (i == 0) {
                    #pragma unroll
                    for (int S = 0; S < 4; ++S)
                        if (x >= S) segc[wid][S][x - S] = h;
                } else {
                    #pragma unroll
                    for (int S = 0; S < 4; ++S)
                        segc[wid][S][x - S] = h;
                }
                float ns = fmaf(s, cd, c * sd);
                float nc = fmaf(c, cd, -(s * sd));
                s = ns; c = nc;
            }
        }

        // ---- FIR as 24x MFMA, 4 independent accumulator chains ----
        v4f CA0 = {0.f, 0.f, 0.f, 0.f};
        v4f CA1 = {0.f, 0.f, 0.f, 0.f};
        v4f CB0 = {0.f, 0.f, 0.f, 0.f};
        v4f CB1 = {0.f, 0.f, 0.f, 0.f};
        #pragma unroll
        for (int t = 0; t < 6; ++t) {
            v4h lo = *(const v4h*)(bbase + 32 * t);
            v4h hi = *(const v4h*)(bbase + 32 * t + 4);
            v8h bf = __builtin_shufflevector(lo, hi, 0, 1, 2, 3, 4, 5, 6, 7);
            CA0 = __builtin_amdgcn_mfma_f32_16x16x32_f16(afrag[t], bf, CA0, 0, 0, 0);
            v4h lo2 = *(const v4h*)(bbase + 256 + 32 * t);
            v4h hi2 = *(const v4h*)(bbase + 256 + 32 * t + 4);
            v8h bf2 = __builtin_shufflevector(lo2, hi2, 0, 1, 2, 3, 4, 5, 6, 7);
            CB0 = __builtin_amdgcn_mfma_f32_16x16x32_f16(afrag[t], bf2, CB0, 0, 0, 0);
        }
        #pragma unroll
        for (int t = 6; t < 12; ++t) {
            v4h lo = *(const v4h*)(bbase + 32 * t);
            v4h hi = *(const v4h*)(bbase + 32 * t + 4);
            v8h bf = __builtin_shufflevector(lo, hi, 0, 1, 2, 3, 4, 5, 6, 7);
            CA1 = __builtin_amdgcn_mfma_f32_16x16x32_f16(afrag[t], bf, CA1, 0, 0, 0);
            v4h lo2 = *(const v4h*)(bbase + 256 + 32 * t);
            v4h hi2 = *(const v4h*)(bbase + 256 + 32 * t + 4);
            v8h bf2 = __builtin_shufflevector(lo2, hi2, 0, 1, 2, 3, 4, 5, 6, 7);
            CB1 = __builtin_amdgcn_mfma_f32_16x16x32_f16(afrag[t], bf2, CB1, 0, 0, 0);
        }

        // ---- tanh + masked accumulate; chunkA p = 64q+16r+m, chunkB p+256 ----
        {
            const int tb = base + 64 * quad + m;
            float y;
            y = CA0[0] + CA1[0]; if (tb +   0 >= 0 && tb +   0 < ol) accA0 += fast_tanh(y);
            y = CA0[1] + CA1[1]; if (tb +  16 >= 0 && tb +  16 < ol) accA1 += fast_tanh(y);
            y = CA0[2] + CA1[2]; if (tb +  32 >= 0 && tb +  32 < ol) accA2 += fast_tanh(y);
            y = CA0[3] + CA1[3]; if (tb +  48 >= 0 && tb +  48 < ol) accA3 += fast_tanh(y);
            y = CB0[0] + CB1[0]; if (tb + 256 >= 0 && tb + 256 < ol) accB0 += fast_tanh(y);
            y = CB0[1] + CB1[1]; if (tb + 272 >= 0 && tb + 272 < ol) accB1 += fast_tanh(y);
            y = CB0[2] + CB1[2]; if (tb + 288 >= 0 && tb + 288 < ol) accB2 += fast_tanh(y);
            y = CB0[3] + CB1[3]; if (tb + 304 >= 0 && tb + 304 < ol) accB3 += fast_tanh(y);
        }
    }

    // ---- per-wave partials -> LDS, one barrier, 4-way sum, coalesced store ----
    {
        const int p = 64 * quad + m;
        red[wid][p +   0] = accA0;
        red[wid][p +  16] = accA1;
        red[wid][p +  32] = accA2;
        red[wid][p +  48] = accA3;
        red[wid][p + 256] = accB0;
        red[wid][p + 272] = accB1;
        red[wid][p + 288] = accB2;
        red[wid][p + 304] = accB3;
    }
    __syncthreads();
    {
        int idx = tid;
        float sum0 = red[0][idx] + red[1][idx] + red[2][idx] + red[3][idx];
        int idx2 = tid + 256;
        float sum1 = red[0][idx2] + red[1][idx2] + red[2][idx2] + red[3][idx2];
        if (o0 + idx  < Dn) out[o0 + idx]  = sum0;
        if (o0 + idx2 < Dn) out[o0 + idx2] = sum1;
    }
}

// ---------------- launcher ----------------
extern "C" void kernel_launch(void* const* d_in, const int* in_sizes, int n_in,
                              void* d_out, int out_size, void* d_ws, size_t ws_size,
                              hipStream_t stream) {
    const float* freq    = (const float*)d_in[0];
    const float* velo    = (const float*)d_in[1];
    const float* w1      = (const float*)d_in[2];
    const float* b1      = (const float*)d_in[3];
    const float* w2      = (const float*)d_in[4];
    const float* b2      = (const float*)d_in[5];
    const float* ws1     = (const float*)d_in[6];
    const float* bs1     = (const float*)d_in[7];
    const float* ws2     = (const float*)d_in[8];
    const float* bs2     = (const float*)d_in[9];
    const float* fir     = (const float*)d_in[10];
    const int*   starts  = (const int*)d_in[11];
    const int*   lengths = (const int*)d_in[12];

    const int N  = in_sizes[0];
    const int Dn = out_size;
    float* out = (float*)d_out;

    float* amps   = (float*)d_ws;
    int*   outlen = (int*)((char*)d_ws + (size_t)N * 8 * sizeof(float));

    params_k<<<(N + 255) / 256, 256, 0, stream>>>(
        freq, velo, w1, b1, w2, b2, ws1, bs1, ws2, bs2,
        starts, lengths, Dn, N, amps, outlen);

    int n_tiles = (Dn + TO - 1) / TO;
    synth_gather_k<<<n_tiles, 256, 0, stream>>>(
        freq, starts, amps, outlen, fir, out, Dn, N);
}

// Round 14
// 144.654 us; speedup vs baseline: 1.0181x; 1.0181x over previous
//
#include <hip/hip_runtime.h>
#include <math.h>

#define LMAX  32768
#define WWIN  1024
#define KFIR  128
#define TO    512                // outputs per block (all 4 waves share them)
#define SEGX  640                // staged samples per pair: t in [base-127, base+513)
#define CPAD  656                // padded shift-copy length (halves); 1312 B (16B mult)
#define NMAX  1024               // max notes

typedef _Float16 v8h __attribute__((ext_vector_type(8)));
typedef _Float16 v4h __attribute__((ext_vector_type(4)));
typedef float    v4f __attribute__((ext_vector_type(4)));

// ---------------- per-note parameter kernel ----------------
// amps pre-multiplied by normalized velocity (exact fold).
__global__ __launch_bounds__(256) void params_k(
    const float* __restrict__ freq, const float* __restrict__ velo,
    const float* __restrict__ w1,  const float* __restrict__ b1,
    const float* __restrict__ w2,  const float* __restrict__ b2,
    const float* __restrict__ ws1, const float* __restrict__ bs1,
    const float* __restrict__ ws2, const float* __restrict__ bs2,
    const int* __restrict__ starts, const int* __restrict__ lengths,
    int Dn, int N,
    float* __restrict__ amps_out, int* __restrict__ outlen_out)
{
    __shared__ float s_w1[32], s_b1[32], s_w2[64], s_b2[2];
    __shared__ float s_ws1[256], s_bs1[64], s_ws2[512], s_bs2[8];

    const int tid = threadIdx.x;
    if (tid < 32)  { s_w1[tid] = w1[tid]; s_b1[tid] = b1[tid]; }
    if (tid < 64)  { s_w2[tid] = w2[tid]; s_bs1[tid] = bs1[tid]; }
    if (tid < 2)   s_b2[tid] = b2[tid];
    if (tid < 8)   s_bs2[tid] = bs2[tid];
    s_ws1[tid] = ws1[tid];
    s_ws2[tid] = ws2[tid];
    s_ws2[tid + 256] = ws2[tid + 256];
    __syncthreads();

    const int n = blockIdx.x * blockDim.x + tid;
    if (n >= N) return;

    int st  = starts[n];
    int len = lengths[n];
    int ol  = min(st + len, Dn) - st;
    ol = max(0, min(ol, LMAX));
    outlen_out[n] = ol;

    float v = velo[n] * (1.0f / 127.0f);
    float nt = (float)st / (float)Dn;

    float lat0 = s_b2[0], lat1 = s_b2[1];
    #pragma unroll
    for (int j = 0; j < 32; ++j) {
        float h = fmaxf(fmaf(nt, s_w1[j], s_b1[j]), 0.0f);
        lat0 = fmaf(h, s_w2[j * 2 + 0], lat0);
        lat1 = fmaf(h, s_w2[j * 2 + 1], lat1);
    }

    const float f0 = freq[n], f1 = v, f2 = lat0, f3 = lat1;

    float acc[8];
    #pragma unroll
    for (int h = 0; h < 8; ++h) acc[h] = s_bs2[h];
    #pragma unroll
    for (int j = 0; j < 64; ++j) {
        float a = s_bs1[j];
        a = fmaf(f0, s_ws1[0 * 64 + j], a);
        a = fmaf(f1, s_ws1[1 * 64 + j], a);
        a = fmaf(f2, s_ws1[2 * 64 + j], a);
        a = fmaf(f3, s_ws1[3 * 64 + j], a);
        a = fmaxf(a, 0.0f);
        #pragma unroll
        for (int h = 0; h < 8; ++h)
            acc[h] = fmaf(a, s_ws2[j * 8 + h], acc[h]);
    }
    #pragma unroll
    for (int h = 0; h < 8; ++h) {
        float a = acc[h];
        float sp = fmaxf(a, 0.0f) + log1pf(expf(-fabsf(a)));
        amps_out[n * 8 + h] = sp * v;            // velocity folded in
    }
}

__device__ __forceinline__ float fast_tanh(float x) {
    float e = __builtin_amdgcn_exp2f(x * 2.8853900817779268f);  // 2*log2(e)
    return fmaf(-2.0f, __builtin_amdgcn_rcpf(e + 1.0f), 1.0f);
}

// ---------------- gather synthesis kernel (MFMA FIR, note-parallel waves) ----------------
// Block = 4 waves serving the SAME 512 outputs; wave w handles notes
// kk = w, w+4, ...  Partial sums in red[wid][512], one barrier, 4-way sum.
// __launch_bounds__(256,3): ~170-VGPR cap.  (256,4) made the allocator
// squeeze to 64 VGPR and spill ~79 MB/dispatch (r13, FETCH 12.8/WRITE 66 MB)
// -- same failure as r8.  This kernel's live set is ~85-100 VGPRs.
__global__ __launch_bounds__(256, 3) void synth_gather_k(
    const float* __restrict__ freq_g, const int* __restrict__ starts,
    const float* __restrict__ amps_g, const int* __restrict__ outlen_g,
    const float* __restrict__ fir,
    float* __restrict__ out, int Dn, int N)
{
    __shared__ __align__(16) _Float16 segc[4][4][CPAD];   // 21 KB
    __shared__ float red[4][TO];                          // 8 KB
    __shared__ float fir_s[KFIR];
    __shared__ unsigned short note_list[NMAX];
    __shared__ int note_cnt;

    const int tid  = threadIdx.x;
    const int wid  = tid >> 6;
    const int lane = tid & 63;
    const int m    = lane & 15;
    const int quad = lane >> 4;
    const int o0   = blockIdx.x * TO;
    const int o_end = min(o0 + TO, Dn);

    if (tid < KFIR) fir_s[tid] = fir[tid];
    if (tid == 0) note_cnt = 0;
    __syncthreads();
    for (int j = tid; j < N; j += 256) {
        int st = starts[j];
        int ol = outlen_g[j];
        if (st < o_end && st + ol > o0) {
            int p = atomicAdd(&note_cnt, 1);
            note_list[p] = (unsigned short)j;
        }
    }
    __syncthreads();
    const int K = note_cnt;

    // ---- A fragments: shifted filter bank (constant for whole kernel) ----
    v8h afrag[12];
    #pragma unroll
    for (int t = 0; t < 12; ++t) {
        v8h af;
        #pragma unroll
        for (int j = 0; j < 8; ++j) {
            int idx = 32 * t + 8 * quad + j - 16 * m;
            float fv = (idx >= 0 && idx < KFIR) ? fir_s[idx] : 0.0f;
            af[j] = (_Float16)fv;
        }
        afrag[t] = af;
    }

    // ---- zero pad tails [636,656) of this wave's shift-copies ----
    for (int z = lane; z < 4 * 20; z += 64) {
        int S = z / 20, off = z % 20;
        segc[wid][S][636 + off] = (_Float16)0.0f;
    }

    // per-lane B read base: copy c = m&3, in-copy half index (m&~3)+8*quad (8B aligned)
    const _Float16* __restrict__ bbase = &segc[wid][m & 3][(m & ~3) + 8 * quad];

    float accA0 = 0.f, accA1 = 0.f, accA2 = 0.f, accA3 = 0.f;
    float accB0 = 0.f, accB1 = 0.f, accB2 = 0.f, accB3 = 0.f;

    const double inv2pi = 0.15915494309189535;
    const float4* __restrict__ amps4 = (const float4*)amps_g;

    // ---- prefetch this wave's pair 0 parameters ----
    int stN = 0, olN = 0; float fN = 0.f;
    float4 amN0 = {}, amN1 = {};
    if (wid < K) {
        const int nid = __builtin_amdgcn_readfirstlane((int)note_list[wid]);
        stN = starts[nid]; olN = outlen_g[nid];
        fN = freq_g[nid];
        amN0 = amps4[nid * 2]; amN1 = amps4[nid * 2 + 1];
    }

    for (int kk = wid; kk < K; kk += 4) {
        const int st = stN, ol = olN;
        const float f = fN;
        const float4 am0 = amN0, am1 = amN1;
        if (kk + 4 < K) {
            const int nid = __builtin_amdgcn_readfirstlane((int)note_list[kk + 4]);
            stN = starts[nid]; olN = outlen_g[nid];
            fN = freq_g[nid];
            amN0 = amps4[nid * 2]; amN1 = amps4[nid * 2 + 1];
        }

        const int base = o0 - st;             // note-local index of tile's first output
        if (base >= ol || base + TO <= 0) continue;   // wave-uniform skip

        const float A0 = am0.x, A1 = am0.y, A2 = am0.z, A3 = am0.w;
        const float A4 = am1.x, A5 = am1.y, A6 = am1.z, A7 = am1.w;
        const double fd = (double)f;

        // phase seed (f64 once per pair) + fixed-angle rotation stepping
        const int tseed = base - 127 + lane;
        double rev0 = fd * (double)tseed * inv2pi;
        float r0 = (float)(rev0 - floor(rev0));
        float s = __builtin_amdgcn_sinf(r0);
        float c = __builtin_amdgcn_cosf(r0);
        double d64 = fd * 64.0 * inv2pi;
        float r64 = (float)(d64 - floor(d64));
        const float sd = __builtin_amdgcn_sinf(r64);
        const float cd = __builtin_amdgcn_cosf(r64);
        const int wbase = ol - WWIN;

        // wave-uniform fast path: no bounds checks, no Hann window
        const bool interior = (base >= 127) && (base + 513 <= wbase);

        if (interior) {
            #pragma unroll
            for (int i = 0; i < 10; ++i) {
                float tc = c + c;
                float sA = s;
                float sum = A0 * sA;
                float sB = tc * sA;              sum = fmaf(A1, sB, sum);
                float sC = fmaf(tc, sB, -sA);    sum = fmaf(A2, sC, sum);
                float sD = fmaf(tc, sC, -sB);    sum = fmaf(A3, sD, sum);
                float sE = fmaf(tc, sD, -sC);    sum = fmaf(A4, sE, sum);
                float sF = fmaf(tc, sE, -sD);    sum = fmaf(A5, sF, sum);
                float sG = fmaf(tc, sF, -sE);    sum = fmaf(A6, sG, sum);
                float sH = fmaf(tc, sG, -sF);    sum = fmaf(A7, sH, sum);
                _Float16 h = (_Float16)sum;
                const int x = lane + 64 * i;
                if (i == 0) {
                    #pragma unroll
                    for (int S = 0; S < 4; ++S)
                        if (x >= S) segc[wid][S][x - S] = h;
                } else {
                    #pragma unroll
                    for (int S = 0; S < 4; ++S)
                        segc[wid][S][x - S] = h;
                }
                float ns = fmaf(s, cd, c * sd);
                float nc = fmaf(c, cd, -(s * sd));
                s = ns; c = nc;
            }
        } else {
            #pragma unroll
            for (int i = 0; i < 10; ++i) {
                int t = tseed + 64 * i;
                float val = 0.0f;
                if (t >= 0 && t < ol) {
                    float tc = c + c;
                    float sA = s;
                    float sum = A0 * sA;
                    float sB = tc * sA;              sum = fmaf(A1, sB, sum);
                    float sC = fmaf(tc, sB, -sA);    sum = fmaf(A2, sC, sum);
                    float sD = fmaf(tc, sC, -sB);    sum = fmaf(A3, sD, sum);
                    float sE = fmaf(tc, sD, -sC);    sum = fmaf(A4, sE, sum);
                    float sF = fmaf(tc, sE, -sD);    sum = fmaf(A5, sF, sum);
                    float sG = fmaf(tc, sF, -sE);    sum = fmaf(A6, sG, sum);
                    float sH = fmaf(tc, sG, -sF);    sum = fmaf(A7, sH, sum);
                    int wpos = t - wbase;
                    float factor = 1.0f;
                    if (wpos >= 0)
                        factor = 0.5f - 0.5f * __builtin_amdgcn_cosf((float)wpos * (1.0f / WWIN));
                    val = sum * factor;
                }
                _Float16 h = (_Float16)val;
                const int x = lane + 64 * i;
                if (i == 0) {
                    #pragma unroll
                    for (int S = 0; S < 4; ++S)
                        if (x >= S) segc[wid][S][x - S] = h;
                } else {
                    #pragma unroll
                    for (int S = 0; S < 4; ++S)
                        segc[wid][S][x - S] = h;
                }
                float ns = fmaf(s, cd, c * sd);
                float nc = fmaf(c, cd, -(s * sd));
                s = ns; c = nc;
            }
        }

        // ---- FIR as 24x MFMA, 4 independent accumulator chains ----
        v4f CA0 = {0.f, 0.f, 0.f, 0.f};
        v4f CA1 = {0.f, 0.f, 0.f, 0.f};
        v4f CB0 = {0.f, 0.f, 0.f, 0.f};
        v4f CB1 = {0.f, 0.f, 0.f, 0.f};
        #pragma unroll
        for (int t = 0; t < 6; ++t) {
            v4h lo = *(const v4h*)(bbase + 32 * t);
            v4h hi = *(const v4h*)(bbase + 32 * t + 4);
            v8h bf = __builtin_shufflevector(lo, hi, 0, 1, 2, 3, 4, 5, 6, 7);
            CA0 = __builtin_amdgcn_mfma_f32_16x16x32_f16(afrag[t], bf, CA0, 0, 0, 0);
            v4h lo2 = *(const v4h*)(bbase + 256 + 32 * t);
            v4h hi2 = *(const v4h*)(bbase + 256 + 32 * t + 4);
            v8h bf2 = __builtin_shufflevector(lo2, hi2, 0, 1, 2, 3, 4, 5, 6, 7);
            CB0 = __builtin_amdgcn_mfma_f32_16x16x32_f16(afrag[t], bf2, CB0, 0, 0, 0);
        }
        #pragma unroll
        for (int t = 6; t < 12; ++t) {
            v4h lo = *(const v4h*)(bbase + 32 * t);
            v4h hi = *(const v4h*)(bbase + 32 * t + 4);
            v8h bf = __builtin_shufflevector(lo, hi, 0, 1, 2, 3, 4, 5, 6, 7);
            CA1 = __builtin_amdgcn_mfma_f32_16x16x32_f16(afrag[t], bf, CA1, 0, 0, 0);
            v4h lo2 = *(const v4h*)(bbase + 256 + 32 * t);
            v4h hi2 = *(const v4h*)(bbase + 256 + 32 * t + 4);
            v8h bf2 = __builtin_shufflevector(lo2, hi2, 0, 1, 2, 3, 4, 5, 6, 7);
            CB1 = __builtin_amdgcn_mfma_f32_16x16x32_f16(afrag[t], bf2, CB1, 0, 0, 0);
        }

        // ---- tanh + masked accumulate; chunkA p = 64q+16r+m, chunkB p+256 ----
        {
            const int tb = base + 64 * quad + m;
            float y;
            y = CA0[0] + CA1[0]; if (tb +   0 >= 0 && tb +   0 < ol) accA0 += fast_tanh(y);
            y = CA0[1] + CA1[1]; if (tb +  16 >= 0 && tb +  16 < ol) accA1 += fast_tanh(y);
            y = CA0[2] + CA1[2]; if (tb +  32 >= 0 && tb +  32 < ol) accA2 += fast_tanh(y);
            y = CA0[3] + CA1[3]; if (tb +  48 >= 0 && tb +  48 < ol) accA3 += fast_tanh(y);
            y = CB0[0] + CB1[0]; if (tb + 256 >= 0 && tb + 256 < ol) accB0 += fast_tanh(y);
            y = CB0[1] + CB1[1]; if (tb + 272 >= 0 && tb + 272 < ol) accB1 += fast_tanh(y);
            y = CB0[2] + CB1[2]; if (tb + 288 >= 0 && tb + 288 < ol) accB2 += fast_tanh(y);
            y = CB0[3] + CB1[3]; if (tb + 304 >= 0 && tb + 304 < ol) accB3 += fast_tanh(y);
        }
    }

    // ---- per-wave partials -> LDS, one barrier, 4-way sum, coalesced store ----
    {
        const int p = 64 * quad + m;
        red[wid][p +   0] = accA0;
        red[wid][p +  16] = accA1;
        red[wid][p +  32] = accA2;
        red[wid][p +  48] = accA3;
        red[wid][p + 256] = accB0;
        red[wid][p + 272] = accB1;
        red[wid][p + 288] = accB2;
        red[wid][p + 304] = accB3;
    }
    __syncthreads();
    {
        int idx = tid;
        float sum0 = red[0][idx] + red[1][idx] + red[2][idx] + red[3][idx];
        int idx2 = tid + 256;
        float sum1 = red[0][idx2] + red[1][idx2] + red[2][idx2] + red[3][idx2];
        if (o0 + idx  < Dn) out[o0 + idx]  = sum0;
        if (o0 + idx2 < Dn) out[o0 + idx2] = sum1;
    }
}

// ---------------- launcher ----------------
extern "C" void kernel_launch(void* const* d_in, const int* in_sizes, int n_in,
                              void* d_out, int out_size, void* d_ws, size_t ws_size,
                              hipStream_t stream) {
    const float* freq    = (const float*)d_in[0];
    const float* velo    = (const float*)d_in[1];
    const float* w1      = (const float*)d_in[2];
    const float* b1      = (const float*)d_in[3];
    const float* w2      = (const float*)d_in[4];
    const float* b2      = (const float*)d_in[5];
    const float* ws1     = (const float*)d_in[6];
    const float* bs1     = (const float*)d_in[7];
    const float* ws2     = (const float*)d_in[8];
    const float* bs2     = (const float*)d_in[9];
    const float* fir     = (const float*)d_in[10];
    const int*   starts  = (const int*)d_in[11];
    const int*   lengths = (const int*)d_in[12];

    const int N  = in_sizes[0];
    const int Dn = out_size;
    float* out = (float*)d_out;

    float* amps   = (float*)d_ws;
    int*   outlen = (int*)((char*)d_ws + (size_t)N * 8 * sizeof(float));

    params_k<<<(N + 255) / 256, 256, 0, stream>>>(
        freq, velo, w1, b1, w2, b2, ws1, bs1, ws2, bs2,
        starts, lengths, Dn, N, amps, outlen);

    int n_tiles = (Dn + TO - 1) / TO;
    synth_gather_k<<<n_tiles, 256, 0, stream>>>(
        freq, starts, amps, outlen, fir, out, Dn, N);
}